// Round 15
// baseline (142.665 us; speedup 1.0000x reference)
//
#include <hip/hip_runtime.h>

// SGAN_PoolingNet: pooled[i] = max_j relu( relu([hidden[j], (ends[j]-ends[i])@We+be] @ W1 + b1) @ W2 + b2 )
// Collapse: y_lin[i,j,:] = A[j,:] - U[i,:]
//   A[j,k] = hidden[j]@W1[0:64,k] + ends[j]@M2[:,k] + b1[k] + be@W1[64:80,k]   (f32 math, stored f16)
//   U[i,k] = ends[i]@M2[:,k],  M2 = We @ W1[64:80,:]  (2x128, f32)
// R18: R14 fat-wave spilled (VGPR pegged 256 = ARCH cap; 512 is unified incl AGPR; WRITE 1280KB
//     scratch). Traffic-halving not refuted -- the reg budget was. Fix: G=4 with upk moved to LDS
//     (the 64-VGPR breaker; only 1KB/block; in-loop ds_read_b128 addr varies only by quad ->
//     4 addrs/instr, 16-lane broadcast each = conflict-free). Budget: bufs 32 + bfrag 64 + mx 64
//     + au 16 + misc ~25 = ~200 < 256 cap. Shape: 256 blocks x 512thr (8 waves, j-split 8-way,
//     8 tiles/wave, launch_bounds(512,2)) = 1 block/CU, 2 waves/SIMD: TLP preserved, traffic
//     128->64MB, free-running depth-2 ring, no in-loop barriers (the property that always won).
//     Tripwire: WRITE_SIZE must stay 256KB; if ~1MB -> spilled -> revert to R5 next.

#define N_AG 1024
#define JT 4

typedef __attribute__((ext_vector_type(8))) _Float16 half8;      // 8 f16 = 4 VGPR (MFMA A/B frag)
typedef __attribute__((ext_vector_type(4))) float floatx4;       // MFMA C/D frag
typedef __attribute__((ext_vector_type(4))) unsigned int uintx4; // 4 packed f16 pairs

__device__ __forceinline__ unsigned short f2h(float f) {
  return __builtin_bit_cast(unsigned short, (_Float16)f);   // RNE
}

// d = max(a - u, 0) elementwise on packed f16 pairs: 2 VALU instrs, no unpack.
__device__ __forceinline__ unsigned pk_sub_relu(unsigned a, unsigned u) {
  unsigned d;
  asm("v_pk_add_f16 %0, %1, %2 neg_lo:[0,1] neg_hi:[0,1]\n\t"
      "v_pk_max_f16 %0, %0, 0"
      : "=v"(d) : "v"(a), "v"(u));
  return d;
}

// ---- prep (R5-exact): block jb computes A[4jb..4jb+3]; block 0 writes M2; blocks 0..31 W2T ----
__global__ __launch_bounds__(128) void prep_all(
    const float* __restrict__ hidden,  // (1,1024,64)
    const float* __restrict__ track,   // (1024,8,2)
    const float* __restrict__ We,      // (2,16)
    const float* __restrict__ be,      // (16)
    const float* __restrict__ W1,      // (80,128)
    const float* __restrict__ b1,      // (128)
    const float* __restrict__ W2,      // (128,64)
    unsigned short* __restrict__ Ah,   // (1024,128) f16
    float* __restrict__ M2f,           // (2,128) f32
    unsigned short* __restrict__ W2T)  // (64,128) f16
{
  const int jb = blockIdx.x;          // 0..255
  const int j0 = jb * JT;
  const int k  = threadIdx.x;         // 0..127
  __shared__ float hs[JT][64];
#pragma unroll
  for (int q = k; q < JT * 64; q += 128) hs[q >> 6][q & 63] = hidden[j0 * 64 + q];
  __syncthreads();

  float m20 = 0.f, m21 = 0.f, cb = b1[k];
#pragma unroll
  for (int t = 0; t < 16; ++t) {
    float w1v = W1[(64 + t) * 128 + k];
    m20 += We[t] * w1v;
    m21 += We[16 + t] * w1v;
    cb  += be[t] * w1v;
  }
  float acc[JT];
#pragma unroll
  for (int jj = 0; jj < JT; ++jj) {
    float e0 = track[(j0 + jj) * 16 + 14];
    float e1 = track[(j0 + jj) * 16 + 15];
    acc[jj] = e0 * m20 + e1 * m21 + cb;
  }
#pragma unroll 8
  for (int t = 0; t < 64; ++t) {
    float w = W1[t * 128 + k];
#pragma unroll
    for (int jj = 0; jj < JT; ++jj) acc[jj] += hs[jj][t] * w;
  }
#pragma unroll
  for (int jj = 0; jj < JT; ++jj)
    __builtin_nontemporal_store(f2h(acc[jj]), &Ah[(j0 + jj) * 128 + k]);

  if (jb == 0) {          // m20/m21 are exactly M2[0][k], M2[1][k]
    M2f[k]       = m20;
    M2f[128 + k] = m21;
  }
  if (jb < 32) {          // W2T[n][c] = f16(W2[c][n]); 32 blocks x 256 entries
#pragma unroll
    for (int q = 0; q < 2; ++q) {
      int idx = jb * 256 + q * 128 + k;
      int n = idx >> 7, c = idx & 127;
      W2T[n * 128 + c] = f2h(W2[c * 64 + n]);
    }
  }
}

// ---- main: one block per 4 agents; 8 waves (2/SIMD), j-split 8-way; upk in LDS ----
__global__ __launch_bounds__(512, 2) void pool_main(
    const unsigned short* __restrict__ Ah,    // (1024,128) f16
    const float* __restrict__ M2f,            // (2,128) f32
    const float* __restrict__ track,          // (1024,8,2) f32
    const unsigned short* __restrict__ W2T,   // (64,128) f16
    const float* __restrict__ b2,             // (64) f32
    float* __restrict__ out)                  // (1024,64) f32
{
  const int tid  = threadIdx.x;
  const int i0   = blockIdx.x * 4;
  const int lane = tid & 63;
  const int w    = tid >> 6;   // wave 0..7: j-tiles jt = 8t + w, t=0..7
  const int m    = lane & 15;  // A row within tile / B-and-D column
  const int quad = lane >> 4;  // k-subrange selector

  // upk table in LDS: [agent][kk*16 + quad*4 + p] packed f16 pairs; 4x64 dwords = 1 KiB.
  __shared__ unsigned upkL[4][64];
  __shared__ float red[8][4][64];    // [wave][agent][col] = 8 KiB

  if (tid < 256) {
    const int g   = tid >> 6;        // agent slot
    const int idx = tid & 63;        // kk*16 + quad*4 + p
    const int kk = idx >> 4, qq = (idx >> 2) & 3, p = idx & 3;
    const int k0 = kk * 32 + qq * 8 + 2 * p;
    const float e0 = track[(i0 + g) * 16 + 14];
    const float e1 = track[(i0 + g) * 16 + 15];
    float a = e0 * M2f[k0]     + e1 * M2f[128 + k0];
    float b = e0 * M2f[k0 + 1] + e1 * M2f[128 + k0 + 1];
    upkL[g][idx] = (unsigned)f2h(a) | ((unsigned)f2h(b) << 16);
  }

  const int TSTEP = 8 * 16 * 128;    // elems between this wave's consecutive tiles
  const unsigned short* base = Ah + (w * 16 + m) * 128 + quad * 8;

  // depth-2 register ring: issue tiles 0,1 ASAP (before barrier; independent of LDS)
  uintx4 buf0[4], buf1[4];
#pragma unroll
  for (int kk = 0; kk < 4; ++kk) buf0[kk] = *(const uintx4*)(base + kk * 32);
#pragma unroll
  for (int kk = 0; kk < 4; ++kk) buf1[kk] = *(const uintx4*)(base + TSTEP + kk * 32);

  // full 64-col B panel (4 x 16-col blocks), register-resident
  half8 bfrag[4][4];
#pragma unroll
  for (int nt = 0; nt < 4; ++nt)
#pragma unroll
    for (int kk = 0; kk < 4; ++kk)
      bfrag[nt][kk] = *(const half8*)(W2T + (nt * 16 + m) * 128 + kk * 32 + quad * 8);

  floatx4 mx[4][4];                  // [agent][nt] = 64 VGPR
#pragma unroll
  for (int g = 0; g < 4; ++g)
#pragma unroll
    for (int nt = 0; nt < 4; ++nt) mx[g][nt] = (floatx4){-3e38f, -3e38f, -3e38f, -3e38f};

  __syncthreads();                   // upkL ready (once, outside the loop)

  const unsigned short* pn = base + 2 * TSTEP;   // next tile to load (t+2)

  // body: 4 agents x {LDS-upk read + repack + 16 MFMA}; prefetch after last BUF use (g=3).
  auto body = [&](uintx4 (&BUF)[4], bool do_load) {
#pragma unroll
    for (int g = 0; g < 4; ++g) {
      uintx4 au[4];
#pragma unroll
      for (int kk = 0; kk < 4; ++kk) {
        // 16B read, addr varies only by quad: 4 addrs, 16-lane broadcast -> conflict-free
        uintx4 up = *(const uintx4*)&upkL[g][kk * 16 + quad * 4];
#pragma unroll
        for (int p = 0; p < 4; ++p) au[kk][p] = pk_sub_relu(BUF[kk][p], up[p]);
      }
      if (g == 3 && do_load) {
#pragma unroll
        for (int kk = 0; kk < 4; ++kk) BUF[kk] = *(const uintx4*)(pn + kk * 32);
        pn += TSTEP;
      }
#pragma unroll
      for (int nt = 0; nt < 4; ++nt) {
        floatx4 acc = (floatx4){0.f, 0.f, 0.f, 0.f};
#pragma unroll
        for (int kk = 0; kk < 4; ++kk)
          acc = __builtin_amdgcn_mfma_f32_16x16x32_f16(
              __builtin_bit_cast(half8, au[kk]), bfrag[nt][kk], acc, 0, 0, 0);
#pragma unroll
        for (int r = 0; r < 4; ++r) mx[g][nt][r] = fmaxf(mx[g][nt][r], acc[r]);
      }
    }
  };

  // 8 tiles/wave, depth-2 ring: t=0..5 load t+2; t=6,7 drain.
#pragma unroll 1
  for (int t2 = 0; t2 < 6; t2 += 2) {
    body(buf0, true);
    body(buf1, true);
  }
  body(buf0, false);   // t=6
  body(buf1, false);   // t=7

  // D layout: row = quad*4 + r (j within tile), col = nt*16 + m. Reduce rows in-lane,
  // quads via shfl, the 8 j-waves via LDS; 4 agents independent.
#pragma unroll
  for (int g = 0; g < 4; ++g)
#pragma unroll
    for (int nt = 0; nt < 4; ++nt) {
      float a = fmaxf(fmaxf(mx[g][nt][0], mx[g][nt][1]), fmaxf(mx[g][nt][2], mx[g][nt][3]));
      a = fmaxf(a, __shfl_xor(a, 16, 64));
      a = fmaxf(a, __shfl_xor(a, 32, 64));
      if (quad == 0) red[w][g][nt * 16 + m] = a;
    }
  __syncthreads();
  if (tid < 256) {
    int g = tid >> 6, n = tid & 63;
    float v = red[0][g][n];
#pragma unroll
    for (int ww = 1; ww < 8; ++ww) v = fmaxf(v, red[ww][g][n]);
    v += b2[n];
    out[(i0 + g) * 64 + n] = v > 0.f ? v : 0.f;
  }
}

extern "C" void kernel_launch(void* const* d_in, const int* in_sizes, int n_in,
                              void* d_out, int out_size, void* d_ws, size_t ws_size,
                              hipStream_t stream) {
  const float* hidden = (const float*)d_in[0]; // (1,1024,64)
  const float* track  = (const float*)d_in[1]; // (1024,8,2)
  const float* We     = (const float*)d_in[2]; // (2,16)
  const float* be     = (const float*)d_in[3]; // (16)
  const float* W1     = (const float*)d_in[4]; // (80,128)
  const float* b1     = (const float*)d_in[5]; // (128)
  const float* W2     = (const float*)d_in[6]; // (128,64)
  const float* b2     = (const float*)d_in[7]; // (64)
  float* out = (float*)d_out;

  char* ws = (char*)d_ws;
  unsigned short* Ah  = (unsigned short*)ws;              // 1024*128*2 = 256 KiB
  float*          M2f = (float*)(ws + 262144);            // 256*4     = 1 KiB
  unsigned short* W2T = (unsigned short*)(ws + 263168);   // 64*128*2  = 16 KiB

  prep_all<<<N_AG / JT, 128, 0, stream>>>(hidden, track, We, be, W1, b1, W2, Ah, M2f, W2T);
  pool_main<<<N_AG / 4, 512, 0, stream>>>(Ah, M2f, track, W2T, b2, out);
}

// Round 16
// 92.264 us; speedup vs baseline: 1.5463x; 1.5463x over previous
//
#include <hip/hip_runtime.h>

// SGAN_PoolingNet: pooled[i] = max_j relu( relu([hidden[j], (ends[j]-ends[i])@We+be] @ W1 + b1) @ W2 + b2 )
// Collapse: y_lin[i,j,:] = A[j,:] - U[i,:]
//   A[j,k] = hidden[j]@W1[0:64,k] + ends[j]@M2[:,k] + b1[k] + be@W1[64:80,k]   (f32 math, stored f16)
//   U[i,k] = ends[i]@M2[:,k],  M2 = We @ W1[64:80,:]  (2x128, f32)
// R19 = FINAL: revert to R5-exact (best measured: 92.2us). Experiment record:
//   R5  G=2, depth-2 reg ring, free-running, JT=4 prep          92.2  <- best
//   R8  + depth-3 ring                                          94.5  null (not prefetch-limited)
//   R12 G=4 + LDS dbuf + per-round barriers                     99.3  barriers expose latency
//   R10 + setprio + JT=2 prep                                   93.0  null
//   R14/R15 fused grid-barrier single kernel                 135/130  straggler serialization
//   R17 G=4 fat-wave (256,1)                                    93.7  spilled (256 arch VGPR cap)
//   R18 G=4 8-wave (512,2)                                     142.7  spilled (128-reg cap: 2nd
//        launch_bounds arg is min waves/EU -> 512thr@2/CU = 4 w/SIMD = 128 VGPR)
// Remaining budget: harness ws-poison fill 40us @ 83% HBM (its own roofline) + ~20us dispatch
// overhead + pool ~27us (latency-bound, 0.4% HBM, 12% MFMA; six structural theories falsified).

#define N_AG 1024
#define JT 4

typedef __attribute__((ext_vector_type(8))) _Float16 half8;      // 8 f16 = 4 VGPR (MFMA A/B frag)
typedef __attribute__((ext_vector_type(4))) float floatx4;       // MFMA C/D frag
typedef __attribute__((ext_vector_type(4))) unsigned int uintx4; // 4 packed f16 pairs

__device__ __forceinline__ unsigned short f2h(float f) {
  return __builtin_bit_cast(unsigned short, (_Float16)f);   // RNE
}

// d = max(a - u, 0) elementwise on packed f16 pairs: 2 VALU instrs, no unpack.
__device__ __forceinline__ unsigned pk_sub_relu(unsigned a, unsigned u) {
  unsigned d;
  asm("v_pk_add_f16 %0, %1, %2 neg_lo:[0,1] neg_hi:[0,1]\n\t"
      "v_pk_max_f16 %0, %0, 0"
      : "=v"(d) : "v"(a), "v"(u));
  return d;
}

// ---- prep: block jb computes A[4jb..4jb+3]; block 0 writes M2; blocks 0..31 write W2T ----
__global__ __launch_bounds__(128) void prep_all(
    const float* __restrict__ hidden,  // (1,1024,64)
    const float* __restrict__ track,   // (1024,8,2)
    const float* __restrict__ We,      // (2,16)
    const float* __restrict__ be,      // (16)
    const float* __restrict__ W1,      // (80,128)
    const float* __restrict__ b1,      // (128)
    const float* __restrict__ W2,      // (128,64)
    unsigned short* __restrict__ Ah,   // (1024,128) f16
    float* __restrict__ M2f,           // (2,128) f32
    unsigned short* __restrict__ W2T)  // (64,128) f16
{
  const int jb = blockIdx.x;          // 0..255
  const int j0 = jb * JT;
  const int k  = threadIdx.x;         // 0..127
  __shared__ float hs[JT][64];
#pragma unroll
  for (int q = k; q < JT * 64; q += 128) hs[q >> 6][q & 63] = hidden[j0 * 64 + q];
  __syncthreads();

  float m20 = 0.f, m21 = 0.f, cb = b1[k];
#pragma unroll
  for (int t = 0; t < 16; ++t) {
    float w1v = W1[(64 + t) * 128 + k];
    m20 += We[t] * w1v;
    m21 += We[16 + t] * w1v;
    cb  += be[t] * w1v;
  }
  float acc[JT];
#pragma unroll
  for (int jj = 0; jj < JT; ++jj) {
    float e0 = track[(j0 + jj) * 16 + 14];
    float e1 = track[(j0 + jj) * 16 + 15];
    acc[jj] = e0 * m20 + e1 * m21 + cb;
  }
#pragma unroll 8
  for (int t = 0; t < 64; ++t) {
    float w = W1[t * 128 + k];
#pragma unroll
    for (int jj = 0; jj < JT; ++jj) acc[jj] += hs[jj][t] * w;
  }
#pragma unroll
  for (int jj = 0; jj < JT; ++jj)
    __builtin_nontemporal_store(f2h(acc[jj]), &Ah[(j0 + jj) * 128 + k]);

  if (jb == 0) {          // m20/m21 are exactly M2[0][k], M2[1][k]
    M2f[k]       = m20;
    M2f[128 + k] = m21;
  }
  if (jb < 32) {          // W2T[n][c] = f16(W2[c][n]); 32 blocks x 256 entries
#pragma unroll
    for (int q = 0; q < 2; ++q) {
      int idx = jb * 256 + q * 128 + k;
      int n = idx >> 7, c = idx & 127;
      W2T[n * 128 + c] = f2h(W2[c * 64 + n]);
    }
  }
}

// ---- main: one block per 2 agents; 4 waves split j 4-way (disjoint), each full 64 cols ----
__global__ __launch_bounds__(256, 2) void pool_main(
    const unsigned short* __restrict__ Ah,    // (1024,128) f16
    const float* __restrict__ M2f,            // (2,128) f32
    const float* __restrict__ track,          // (1024,8,2) f32
    const unsigned short* __restrict__ W2T,   // (64,128) f16
    const float* __restrict__ b2,             // (64) f32
    float* __restrict__ out)                  // (1024,64) f32
{
  const int i0   = blockIdx.x * 2;
  const int lane = threadIdx.x & 63;
  const int w    = threadIdx.x >> 6;   // wave 0..3: j-tiles jt = 4t + w
  const int m    = lane & 15;          // A row within tile / B-and-D column
  const int quad = lane >> 4;          // k-subrange selector

  const int TSTEP = 4 * 16 * 128;      // elems between this wave's consecutive tiles
  const unsigned short* base = Ah + (w * 16 + m) * 128 + quad * 8;

  // depth-2 register ring: issue tiles 0,1 of this wave ASAP
  uintx4 buf0[4], buf1[4];
#pragma unroll
  for (int kk = 0; kk < 4; ++kk) buf0[kk] = *(const uintx4*)(base + kk * 32);
#pragma unroll
  for (int kk = 0; kk < 4; ++kk) buf1[kk] = *(const uintx4*)(base + TSTEP + kk * 32);

  // U[i0], U[i0+1] as packed f16 pairs matching A's dword element order
  const float a0 = track[i0 * 16 + 14];
  const float a1 = track[i0 * 16 + 15];
  const float c0 = track[(i0 + 1) * 16 + 14];
  const float c1 = track[(i0 + 1) * 16 + 15];
  unsigned upkA[4][4], upkB[4][4];
#pragma unroll
  for (int kk = 0; kk < 4; ++kk) {
#pragma unroll
    for (int p = 0; p < 4; ++p) {
      int k0 = kk * 32 + quad * 8 + 2 * p;
      float m0 = M2f[k0],     m0h = M2f[128 + k0];
      float m1 = M2f[k0 + 1], m1h = M2f[128 + k0 + 1];
      upkA[kk][p] = (unsigned)f2h(a0 * m0 + a1 * m0h) | ((unsigned)f2h(a0 * m1 + a1 * m1h) << 16);
      upkB[kk][p] = (unsigned)f2h(c0 * m0 + c1 * m0h) | ((unsigned)f2h(c0 * m1 + c1 * m1h) << 16);
    }
  }

  // full 64-col B panel per wave (4 x 16-col blocks), register/AGPR-resident
  half8 bfrag[4][4];
#pragma unroll
  for (int nt = 0; nt < 4; ++nt)
#pragma unroll
    for (int kk = 0; kk < 4; ++kk)
      bfrag[nt][kk] = *(const half8*)(W2T + (nt * 16 + m) * 128 + kk * 32 + quad * 8);

  floatx4 mxA[4], mxB[4];
#pragma unroll
  for (int nt = 0; nt < 4; ++nt) {
    mxA[nt] = (floatx4){-3e38f, -3e38f, -3e38f, -3e38f};
    mxB[nt] = (floatx4){-3e38f, -3e38f, -3e38f, -3e38f};
  }

  const unsigned short* pn = base + 2 * TSTEP;   // next tile to load (t+2)

#define POOL_BODY(BUF, DO_LOAD)                                               \
  {                                                                           \
    uintx4 au[4];                                                             \
    _Pragma("unroll") for (int kk = 0; kk < 4; ++kk)                          \
      _Pragma("unroll") for (int p = 0; p < 4; ++p)                           \
        au[kk][p] = pk_sub_relu(BUF[kk][p], upkA[kk][p]);                     \
    _Pragma("unroll") for (int nt = 0; nt < 4; ++nt) {                        \
      floatx4 acc = (floatx4){0.f, 0.f, 0.f, 0.f};                            \
      _Pragma("unroll") for (int kk = 0; kk < 4; ++kk)                        \
        acc = __builtin_amdgcn_mfma_f32_16x16x32_f16(                         \
            __builtin_bit_cast(half8, au[kk]), bfrag[nt][kk], acc, 0, 0, 0);  \
      _Pragma("unroll") for (int r = 0; r < 4; ++r)                           \
        mxA[nt][r] = fmaxf(mxA[nt][r], acc[r]);                               \
    }                                                                         \
    _Pragma("unroll") for (int kk = 0; kk < 4; ++kk)                          \
      _Pragma("unroll") for (int p = 0; p < 4; ++p)                           \
        au[kk][p] = pk_sub_relu(BUF[kk][p], upkB[kk][p]);                     \
    if (DO_LOAD) {                                                            \
      _Pragma("unroll") for (int kk = 0; kk < 4; ++kk)                        \
        BUF[kk] = *(const uintx4*)(pn + kk * 32);                             \
      pn += TSTEP;                                                            \
    }                                                                         \
    _Pragma("unroll") for (int nt = 0; nt < 4; ++nt) {                        \
      floatx4 acc = (floatx4){0.f, 0.f, 0.f, 0.f};                            \
      _Pragma("unroll") for (int kk = 0; kk < 4; ++kk)                        \
        acc = __builtin_amdgcn_mfma_f32_16x16x32_f16(                         \
            __builtin_bit_cast(half8, au[kk]), bfrag[nt][kk], acc, 0, 0, 0);  \
      _Pragma("unroll") for (int r = 0; r < 4; ++r)                           \
        mxB[nt][r] = fmaxf(mxB[nt][r], acc[r]);                               \
    }                                                                         \
  }

#pragma unroll 1
  for (int t2 = 0; t2 < 14; t2 += 2) {
    POOL_BODY(buf0, true)
    POOL_BODY(buf1, true)
  }
  POOL_BODY(buf0, false)   // t=14
  POOL_BODY(buf1, false)   // t=15
#undef POOL_BODY

  // D layout: row = quad*4 + r (j within tile), col = nt*16 + m. Reduce rows in-lane,
  // across quads via shfl, across the 4 j-waves via LDS. Two agents' results side by side.
  __shared__ float red[2][4][64];
#pragma unroll
  for (int nt = 0; nt < 4; ++nt) {
    float a = fmaxf(fmaxf(mxA[nt][0], mxA[nt][1]), fmaxf(mxA[nt][2], mxA[nt][3]));
    a = fmaxf(a, __shfl_xor(a, 16, 64));
    a = fmaxf(a, __shfl_xor(a, 32, 64));
    float b = fmaxf(fmaxf(mxB[nt][0], mxB[nt][1]), fmaxf(mxB[nt][2], mxB[nt][3]));
    b = fmaxf(b, __shfl_xor(b, 16, 64));
    b = fmaxf(b, __shfl_xor(b, 32, 64));
    if (quad == 0) {
      red[0][w][nt * 16 + m] = a;
      red[1][w][nt * 16 + m] = b;
    }
  }
  __syncthreads();
  if (threadIdx.x < 128) {
    int g = threadIdx.x >> 6, n = threadIdx.x & 63;
    float v = fmaxf(fmaxf(red[g][0][n], red[g][1][n]), fmaxf(red[g][2][n], red[g][3][n]));
    v += b2[n];
    out[(i0 + g) * 64 + n] = v > 0.f ? v : 0.f;
  }
}

extern "C" void kernel_launch(void* const* d_in, const int* in_sizes, int n_in,
                              void* d_out, int out_size, void* d_ws, size_t ws_size,
                              hipStream_t stream) {
  const float* hidden = (const float*)d_in[0]; // (1,1024,64)
  const float* track  = (const float*)d_in[1]; // (1024,8,2)
  const float* We     = (const float*)d_in[2]; // (2,16)
  const float* be     = (const float*)d_in[3]; // (16)
  const float* W1     = (const float*)d_in[4]; // (80,128)
  const float* b1     = (const float*)d_in[5]; // (128)
  const float* W2     = (const float*)d_in[6]; // (128,64)
  const float* b2     = (const float*)d_in[7]; // (64)
  float* out = (float*)d_out;

  char* ws = (char*)d_ws;
  unsigned short* Ah  = (unsigned short*)ws;              // 1024*128*2 = 256 KiB
  float*          M2f = (float*)(ws + 262144);            // 256*4     = 1 KiB
  unsigned short* W2T = (unsigned short*)(ws + 263168);   // 64*128*2  = 16 KiB

  prep_all<<<N_AG / JT, 128, 0, stream>>>(hidden, track, We, be, W1, b1, W2, Ah, M2f, W2T);
  pool_main<<<N_AG / 2, 256, 0, stream>>>(Ah, M2f, track, W2T, b2, out);
}